// Round 5
// baseline (146.161 us; speedup 1.0000x reference)
//
#include <hip/hip_runtime.h>
#include <hip/hip_bf16.h>
#include <math.h>

#define N_NODES 100000
#define N_PAD   100032      // 1563 * 64, multiple of 32
#define F_IN    100
#define HID     128
#define NCLS    64
#define KA      256         // padded K for layer-1 A rows: [agg(100)|0|x(100)|0]
#define XOFF    128         // x part starts at element 128
#define NTILES  (N_PAD / 32)
#define GRID_F  782         // 4 sequential tiles per block

typedef __attribute__((ext_vector_type(8))) short bf16x8;
typedef __attribute__((ext_vector_type(4))) float f32x4;

// Pin a loaded value in VGPRs: asm "modifies" it, so the compiler can neither
// rematerialize it from memory nor sink the load to the use point.
#define KEEP(x) asm volatile("" : "+v"(x))

static __device__ __forceinline__ ushort f2bf(float f) {
    union { float f; unsigned u; } v; v.f = f;
    unsigned r = (v.u + 0x7FFFu + ((v.u >> 16) & 1u)) >> 16;
    return (ushort)r;
}
static __device__ __forceinline__ float bflo(unsigned u) {
    union { unsigned u; float f; } v; v.u = u << 16; return v.f;
}
static __device__ __forceinline__ float bfhi(unsigned u) {
    union { unsigned u; float f; } v; v.u = u & 0xFFFF0000u; return v.f;
}
static __device__ __forceinline__ float bf2f(ushort u) {
    union { unsigned u; float f; } v; v.u = ((unsigned)u) << 16; return v.f;
}

// ---------------- row_ptr via binary search over sorted rows ----------------
__global__ void rowptr_kernel(const int* __restrict__ rows, int* __restrict__ row_ptr,
                              int n_nodes, int n_edges) {
    int i = blockIdx.x * blockDim.x + threadIdx.x;
    if (i > n_nodes) return;
    int lo = 0, hi = n_edges;
    while (lo < hi) {
        int mid = (lo + hi) >> 1;
        if (rows[mid] < i) lo = mid + 1; else hi = mid;
    }
    row_ptr[i] = lo;
}

// ------------- prep: x -> Abf[:, 100:256] bf16 (4 cols per thread) ----------
__global__ __launch_bounds__(256) void prep_x_kernel(const float* __restrict__ x,
                                                     ushort* __restrict__ Abf) {
    int i = blockIdx.x * 256 + threadIdx.x;          // over N_PAD * 39
    if (i >= N_PAD * 39) return;
    int node = i / 39;
    int gcol = i - node * 39;
    int col = 100 + gcol * 4;                        // 100..252, step 4
    ushort4 o = {0, 0, 0, 0};
    if (node < N_NODES && col >= XOFF && col < XOFF + F_IN) {
        float4 v = *(const float4*)(x + (size_t)node * F_IN + (col - XOFF));
        o.x = f2bf(v.x); o.y = f2bf(v.y); o.z = f2bf(v.z); o.w = f2bf(v.w);
    }
    *(ushort4*)(Abf + (size_t)node * KA + col) = o;
}

// ------------- prep: zero the pad-node rows of Abf (cols 0..255) ------------
__global__ __launch_bounds__(256) void pad_zero_kernel(ushort* __restrict__ Abf) {
    int i = blockIdx.x * 256 + threadIdx.x;          // over 32 * 64 (8B chunks)
    if (i >= (N_PAD - N_NODES) * (KA / 4)) return;
    ((ushort4*)(Abf + (size_t)N_NODES * KA))[i] = (ushort4){0, 0, 0, 0};
}

// ------------- prep: weights/bias, bf16, with row interleave ----------------
// storage row s -> original row jorig = (s & ~31) + 2*(s&15) + ((s>>4)&1),
// so that MFMA frag o of lane m yields original output col 2m+o (adjacent).
__global__ __launch_bounds__(256) void prep_w_kernel(
    const float* __restrict__ Wl1, const float* __restrict__ bl1,
    const float* __restrict__ Wr1, const float* __restrict__ br1,
    const float* __restrict__ Wl2, const float* __restrict__ bl2,
    const float* __restrict__ Wr2, const float* __restrict__ br2,
    ushort* __restrict__ W1, ushort* __restrict__ W2,
    float* __restrict__ b1, float* __restrict__ b2) {
    int tid = blockIdx.x * 256 + threadIdx.x;
    int stride = gridDim.x * 256;
    for (int i = tid; i < HID * KA; i += stride) {       // W1: [128][256]
        int s = i >> 8, k = i & 255;
        int j = (s & ~31) + 2 * (s & 15) + ((s >> 4) & 1);
        float v = 0.f;
        if (k < F_IN) v = Wl1[j * F_IN + k];
        else if (k >= XOFF && k < XOFF + F_IN) v = Wr1[j * F_IN + (k - XOFF)];
        W1[i] = f2bf(v);
    }
    for (int i = tid; i < HID * HID; i += stride) {      // W2: [128][128]
        int s = i >> 7, k = i & 127;
        int j = (s & ~31) + 2 * (s & 15) + ((s >> 4) & 1);
        float v = (j < NCLS) ? Wl2[j * HID + k] : Wr2[(j - NCLS) * HID + k];
        W2[i] = f2bf(v);
    }
    if (tid < HID) b1[tid] = bl1[tid] + br1[tid];
    if (tid < NCLS) b2[tid] = bl2[tid] + br2[tid];
}

// ---- SpMM 1: Abf[node][0:100] = sum_e val * Abf[col][128:228], bf16 --------
// One wave per node. TWO edges per divergent gather instruction: lanes 0-31
// carry edge e (even), lanes 32-63 edge e+1 (odd); each lane gathers uint2
// (4 feats). Addresses come from DIRECT per-half cols/vals loads (one cache
// line, no shuffles -> no crossbar op in the address chain; round-4 shuffles
// regressed). Halves combined once at the end via shfl_xor(32).
__global__ __launch_bounds__(256) void spmm1_kernel(
    const float* __restrict__ vals, const int* __restrict__ cols,
    const int* __restrict__ row_ptr, ushort* __restrict__ Abf) {
    int node = blockIdx.x * 4 + (threadIdx.x >> 6);
    if (node >= N_NODES) return;
    int lane = threadIdx.x & 63;
    int s = __builtin_amdgcn_readfirstlane(row_ptr[node]);
    int e = __builtin_amdgcn_readfirstlane(row_ptr[node + 1]);
    int half = lane >> 5;
    int fl = lane & 31;                          // fl<25 carry useful feats
    const ushort* xb = Abf + XOFF + fl * 4;      // 4 feats per lane (8B)

    float acc[2][4] = {{0.f, 0.f, 0.f, 0.f}, {0.f, 0.f, 0.f, 0.f}};
    int i = s;
    for (; i + 8 <= e; i += 8) {                 // 8 edges: 4 instrs x 2 halves
        uint2 u[4]; float v[4];
#pragma unroll
        for (int q = 0; q < 4; ++q) {
            int eidx = i + 2 * q + half;
            int c = cols[eidx];
            v[q] = vals[eidx];
            u[q] = *(const uint2*)(xb + (size_t)c * KA);
        }
#pragma unroll
        for (int q = 0; q < 4; ++q) {
            acc[q & 1][0] += v[q] * bflo(u[q].x);
            acc[q & 1][1] += v[q] * bfhi(u[q].x);
            acc[q & 1][2] += v[q] * bflo(u[q].y);
            acc[q & 1][3] += v[q] * bfhi(u[q].y);
        }
    }
    for (; i + 2 <= e; i += 2) {                 // pair tail
        int eidx = i + half;
        int c = cols[eidx];
        float v = vals[eidx];
        uint2 u = *(const uint2*)(xb + (size_t)c * KA);
        acc[0][0] += v * bflo(u.x);
        acc[0][1] += v * bfhi(u.x);
        acc[0][2] += v * bflo(u.y);
        acc[0][3] += v * bfhi(u.y);
    }
    if (i < e) {                                 // odd leftover: half 0 only
        int c = cols[i];
        float v = half ? 0.f : vals[i];
        uint2 u = *(const uint2*)(xb + (size_t)c * KA);
        acc[1][0] += v * bflo(u.x);
        acc[1][1] += v * bfhi(u.x);
        acc[1][2] += v * bflo(u.y);
        acc[1][3] += v * bfhi(u.y);
    }
    float r[4];
#pragma unroll
    for (int j = 0; j < 4; ++j) {
        float tj = acc[0][j] + acc[1][j];
        tj += __shfl_xor(tj, 32);
        r[j] = tj;
    }
    if (half == 0 && fl < 25) {
        ushort4 o = {f2bf(r[0]), f2bf(r[1]), f2bf(r[2]), f2bf(r[3])};
        *(ushort4*)(Abf + (size_t)node * KA + fl * 4) = o;
    }
}

// ---- Fused GEMM: LDS-staged A (shared by 4 waves), KEEP-pinned W -----------
// Block: 4 waves, 4 sequential 32-node tiles. Per tile:
//   - A-tile (32x256 bf16 = 16KB) staged ONCE into LDS (coalesced
//     global_load_dwordx4 -> XOR-swizzled ds_write_b128), read by all 4
//     waves via swizzled ds_read_b128 (2-way bank alias = free).
//   - W frags pinned in VGPRs via KEEP asm (prevents the compiler's
//     min-pressure schedule that re-loads W before every MFMA: r2 showed
//     VGPR_Count=44 with every fragment load sunk to its use).
//   - L1-norm deferred to the epilogue; one barrier per tile; A/h/part
//     double-buffered so tiles pipeline without a bottom barrier.
__global__ __launch_bounds__(256, 2) void gemm_fused_kernel(
    const ushort* __restrict__ Abf, const ushort* __restrict__ W1,
    const ushort* __restrict__ W2, const float* __restrict__ b1,
    ushort* __restrict__ t, ushort* __restrict__ rb) {
    __shared__ char Ald[2][16384];                   // dbuf: 32 nodes x 256 bf16
    __shared__ char h_lds[2][8192];                  // dbuf: 32 nodes x 128 bf16
    __shared__ __align__(16) float part[2][32][4];   // [buf][node][wave] L1 partials
    int lane = threadIdx.x & 63;
    int w = threadIdx.x >> 6;
    int m = lane & 15, g = lane >> 4;

    int t0 = blockIdx.x * 4;
    int ntl = NTILES - t0; if (ntl > 4) ntl = 4;     // 1..4 tiles (last block: 2)

    // ---- W frags: loaded once, pinned ----
    bf16x8 wf1[2][8];
    bf16x8 wf2[2][4];
#pragma unroll
    for (int o = 0; o < 2; ++o) {
        const ushort* wrow = W1 + (size_t)(w * 32 + o * 16 + m) * KA + g * 8;
#pragma unroll
        for (int kb = 0; kb < 8; ++kb) wf1[o][kb] = *(const bf16x8*)(wrow + kb * 32);
    }
#pragma unroll
    for (int o = 0; o < 2; ++o) {
        const ushort* wrow = W2 + (size_t)(w * 32 + o * 16 + m) * HID + g * 8;
#pragma unroll
        for (int kb = 0; kb < 4; ++kb) wf2[o][kb] = *(const bf16x8*)(wrow + kb * 32);
    }
#pragma unroll
    for (int o = 0; o < 2; ++o) {
#pragma unroll
        for (int kb = 0; kb < 8; ++kb) KEEP(wf1[o][kb]);
#pragma unroll
        for (int kb = 0; kb < 4; ++kb) KEEP(wf2[o][kb]);
    }
    float bias0 = b1[w * 32 + 2 * m + 0];
    float bias1 = b1[w * 32 + 2 * m + 1];

    // ---- prologue: stage tile t0 into Ald[0] ----
    bf16x8 st[4];
#pragma unroll
    for (int i = 0; i < 4; ++i)
        st[i] = *(const bf16x8*)(Abf + (size_t)t0 * 8192 + ((w * 4 + i) * 64 + lane) * 8);
#pragma unroll
    for (int i = 0; i < 4; ++i) {
        int r = w * 4 + i;
        int nl = r * 2 + (lane >> 5);
        int dst = nl * 512 + ((((lane & 31) ^ (nl & 7))) << 4);
        *(bf16x8*)(&Ald[0][0] + dst) = st[i];
    }
    __syncthreads();

    for (int j = 0; ; ) {
        int buf = j & 1;
        int base = (t0 + j) * 32;
        bool last = (j + 1 >= ntl);

        // ---- issue next tile's global loads (hide under phase 1) ----
        if (!last) {
#pragma unroll
            for (int i = 0; i < 4; ++i)
                st[i] = *(const bf16x8*)(Abf + (size_t)(t0 + j + 1) * 8192 +
                                         ((w * 4 + i) * 64 + lane) * 8);
        }

        // ---- phase 1: layer-1 MFMAs, A from LDS (swizzled reads) ----
        f32x4 acc1[2][2];
#pragma unroll
        for (int mt = 0; mt < 2; ++mt)
#pragma unroll
            for (int o = 0; o < 2; ++o) acc1[mt][o] = (f32x4){0.f, 0.f, 0.f, 0.f};
#pragma unroll
        for (int mt = 0; mt < 2; ++mt) {
            int nl = mt * 16 + m;
            int rowb = nl * 512;
            int swz = (nl & 7) << 4;
#pragma unroll
            for (int kb = 0; kb < 8; ++kb) {
                bf16x8 a = *(const bf16x8*)(&Ald[buf][0] + rowb + ((((g + 4 * kb)) << 4) ^ swz));
                acc1[mt][0] = __builtin_amdgcn_mfma_f32_16x16x32_bf16(a, wf1[0][kb], acc1[mt][0], 0, 0, 0);
                acc1[mt][1] = __builtin_amdgcn_mfma_f32_16x16x32_bf16(a, wf1[1][kb], acc1[mt][1], 0, 0, 0);
            }
        }

        // ---- write next A-tile into the other LDS buffer ----
        if (!last) {
#pragma unroll
            for (int i = 0; i < 4; ++i) {
                int r = w * 4 + i;
                int nl = r * 2 + (lane >> 5);
                int dst = nl * 512 + ((((lane & 31) ^ (nl & 7))) << 4);
                *(bf16x8*)(&Ald[buf ^ 1][0] + dst) = st[i];
            }
        }

        // ---- bias; relu(h) -> h_lds (UN-normalized); partial L1 ----
        float sr[2][4];
#pragma unroll
        for (int mt = 0; mt < 2; ++mt)
#pragma unroll
            for (int r = 0; r < 4; ++r) {
                acc1[mt][0][r] += bias0;
                acc1[mt][1][r] += bias1;
                sr[mt][r] = fabsf(acc1[mt][0][r]) + fabsf(acc1[mt][1][r]);
                int nl = mt * 16 + g * 4 + r;
                unsigned lo = f2bf(fmaxf(acc1[mt][0][r], 0.f));
                unsigned hi = f2bf(fmaxf(acc1[mt][1][r], 0.f));
                int off = (nl * 256 + w * 64 + m * 4) ^ ((nl & 7) << 4);
                *(unsigned*)(&h_lds[buf][0] + off) = (hi << 16) | lo;
            }
#pragma unroll
        for (int off = 1; off < 16; off <<= 1)
#pragma unroll
            for (int mt = 0; mt < 2; ++mt)
#pragma unroll
                for (int r = 0; r < 4; ++r) sr[mt][r] += __shfl_xor(sr[mt][r], off);
        if (m == 0) {
#pragma unroll
            for (int mt = 0; mt < 2; ++mt)
#pragma unroll
                for (int r = 0; r < 4; ++r) part[buf][mt * 16 + g * 4 + r][w] = sr[mt][r];
        }
        __syncthreads();        // single barrier/tile: h+part+next-A visible

        // ---- phase 2: layer-2 MFMAs from LDS relu(h) ----
        f32x4 acc2[2][2];
#pragma unroll
        for (int mt = 0; mt < 2; ++mt)
#pragma unroll
            for (int o = 0; o < 2; ++o) acc2[mt][o] = (f32x4){0.f, 0.f, 0.f, 0.f};
#pragma unroll
        for (int mt = 0; mt < 2; ++mt) {
            int nl = mt * 16 + m;
            bf16x8 a[4];
#pragma unroll
            for (int kb = 0; kb < 4; ++kb) {
                int off = (nl * 256 + g * 16 + kb * 64) ^ ((nl & 7) << 4);
                a[kb] = *(const bf16x8*)(&h_lds[buf][0] + off);
            }
#pragma unroll
            for (int kb = 0; kb < 4; ++kb) {
                acc2[mt][0] = __builtin_amdgcn_mfma_f32_16x16x32_bf16(a[kb], wf2[0][kb], acc2[mt][0], 0, 0, 0);
                acc2[mt][1] = __builtin_amdgcn_mfma_f32_16x16x32_bf16(a[kb], wf2[1][kb], acc2[mt][1], 0, 0, 0);
            }
        }

        // ---- epilogue: deferred 1/||h||_1, packed dword stores ----
        ushort* obuf = (w < 2) ? t : rb;
        int colb = (w & 1) * 32 + 2 * m;
#pragma unroll
        for (int mt = 0; mt < 2; ++mt)
#pragma unroll
            for (int r = 0; r < 4; ++r) {
                int nl = mt * 16 + g * 4 + r;
                int node = base + nl;
                float4 p = *(const float4*)&part[buf][nl][0];
                float inv = 1.f / fmaxf((p.x + p.y) + (p.z + p.w), 1e-12f);
                unsigned lo = f2bf(acc2[mt][0][r] * inv);
                unsigned hi = f2bf(acc2[mt][1][r] * inv);
                *(unsigned*)(obuf + (size_t)node * NCLS + colb) = (hi << 16) | lo;
            }

        if (last) break;
        ++j;
    }
}

// ---- SpMM 2 on t (bf16, D=64) + rb + bias, fused log_softmax ---------------
// FOUR edges per divergent gather instruction: quarter qt = lane>>4 handles
// edge e+qt; lane fl = lane&15 gathers uint2 (cols fl*4..fl*4+3, 8B; 16 lanes
// x 8B = the full 128B row). Addresses from DIRECT per-quarter cols/vals
// loads (one line, no shuffles). Quarter partials combined once at the end
// via shfl_xor(16)+shfl_xor(32); softmax across 16 lanes x 4 cols.
__global__ __launch_bounds__(256) void spmm2_kernel(
    const float* __restrict__ vals, const int* __restrict__ cols,
    const int* __restrict__ row_ptr, const ushort* __restrict__ t,
    const ushort* __restrict__ rb, const float* __restrict__ b2,
    float* __restrict__ out) {
    int node = blockIdx.x * 4 + (threadIdx.x >> 6);
    if (node >= N_NODES) return;
    int lane = threadIdx.x & 63;
    int s = __builtin_amdgcn_readfirstlane(row_ptr[node]);
    int e = __builtin_amdgcn_readfirstlane(row_ptr[node + 1]);
    int qt = lane >> 4;
    int fl = lane & 15;                          // covers cols 4fl..4fl+3
    const ushort* tb = t + fl * 4;

    float a0 = 0.f, a1 = 0.f, a2 = 0.f, a3 = 0.f;
    int i = s;
    for (; i + 8 <= e; i += 8) {                 // 8 edges: 2 instrs x 4 qts
        uint2 u[2]; float v[2];
#pragma unroll
        for (int q = 0; q < 2; ++q) {
            int eidx = i + 4 * q + qt;
            int c = cols[eidx];
            v[q] = vals[eidx];
            u[q] = *(const uint2*)(tb + (size_t)c * NCLS);
        }
#pragma unroll
        for (int q = 0; q < 2; ++q) {
            a0 += v[q] * bflo(u[q].x);
            a1 += v[q] * bfhi(u[q].x);
            a2 += v[q] * bflo(u[q].y);
            a3 += v[q] * bfhi(u[q].y);
        }
    }
    if (i + 4 <= e) {                            // quad tail
        int eidx = i + qt;
        int c = cols[eidx];
        float v = vals[eidx];
        uint2 u = *(const uint2*)(tb + (size_t)c * NCLS);
        a0 += v * bflo(u.x);
        a1 += v * bfhi(u.x);
        a2 += v * bflo(u.y);
        a3 += v * bfhi(u.y);
        i += 4;
    }
    if (i < e) {                                 // 1..3 leftover, clamp+mask
        int eidx = i + qt;
        bool ok = eidx < e;
        int c = cols[ok ? eidx : e - 1];
        float v = ok ? vals[eidx] : 0.f;
        uint2 u = *(const uint2*)(tb + (size_t)c * NCLS);
        a0 += v * bflo(u.x);
        a1 += v * bfhi(u.x);
        a2 += v * bflo(u.y);
        a3 += v * bfhi(u.y);
    }
    // combine quarters: lanes with same fl across qt groups hold same cols
    a0 += __shfl_xor(a0, 16); a0 += __shfl_xor(a0, 32);
    a1 += __shfl_xor(a1, 16); a1 += __shfl_xor(a1, 32);
    a2 += __shfl_xor(a2, 16); a2 += __shfl_xor(a2, 32);
    a3 += __shfl_xor(a3, 16); a3 += __shfl_xor(a3, 32);

    uint2 rbu = *(const uint2*)(rb + (size_t)node * NCLS + fl * 4);
    float4 bb = *(const float4*)(b2 + fl * 4);
    a0 += bflo(rbu.x) + bb.x;
    a1 += bfhi(rbu.x) + bb.y;
    a2 += bflo(rbu.y) + bb.z;
    a3 += bfhi(rbu.y) + bb.w;

    // log_softmax over 64 cols = 16 lanes x 4 (duplicated across qt groups)
    float mx = fmaxf(fmaxf(a0, a1), fmaxf(a2, a3));
#pragma unroll
    for (int off = 1; off < 16; off <<= 1) mx = fmaxf(mx, __shfl_xor(mx, off));
    float ss = expf(a0 - mx) + expf(a1 - mx) + expf(a2 - mx) + expf(a3 - mx);
#pragma unroll
    for (int off = 1; off < 16; off <<= 1) ss += __shfl_xor(ss, off);
    float ls = mx + logf(ss);
    if (qt == 0) {
        float4 o = {a0 - ls, a1 - ls, a2 - ls, a3 - ls};
        *(float4*)(out + (size_t)node * NCLS + fl * 4) = o;
    }
}

extern "C" void kernel_launch(void* const* d_in, const int* in_sizes, int n_in,
                              void* d_out, int out_size, void* d_ws, size_t ws_size,
                              hipStream_t stream) {
    const float* x         = (const float*)d_in[0];
    const float* edge_vals = (const float*)d_in[1];
    const float* Wl1       = (const float*)d_in[2];
    const float* bl1       = (const float*)d_in[3];
    const float* Wr1       = (const float*)d_in[4];
    const float* br1       = (const float*)d_in[5];
    const float* Wl2       = (const float*)d_in[6];
    const float* bl2       = (const float*)d_in[7];
    const float* Wr2       = (const float*)d_in[8];
    const float* br2       = (const float*)d_in[9];
    const int* edge_rows   = (const int*)d_in[10];
    const int* edge_cols   = (const int*)d_in[11];
    float* out = (float*)d_out;

    int n_edges = in_sizes[1];

    char* ws = (char*)d_ws;
    int*    row_ptr = (int*)(ws + 0);                        // 400 KB
    ushort* Abf     = (ushort*)(ws + (1u << 20));            // N_PAD*256*2 = 51.2 MB
    ushort* t_buf   = (ushort*)(ws + 52264960u);             // N_PAD*64*2 = 12.8 MB
    ushort* r_buf   = (ushort*)(ws + 65069056u);             // 12.8 MB
    ushort* W1      = (ushort*)(ws + 77873152u);             // 64 KB
    ushort* W2      = (ushort*)(ws + 77938688u);             // 32 KB
    float*  b1      = (float*)(ws + 77971456u);              // 512 B
    float*  b2      = (float*)(ws + 77971968u);              // 256 B

    rowptr_kernel<<<(N_NODES + 1 + 255) / 256, 256, 0, stream>>>(
        edge_rows, row_ptr, N_NODES, n_edges);
    prep_x_kernel<<<(N_PAD * 39 + 255) / 256, 256, 0, stream>>>(x, Abf);
    pad_zero_kernel<<<8, 256, 0, stream>>>(Abf);
    prep_w_kernel<<<64, 256, 0, stream>>>(Wl1, bl1, Wr1, br1, Wl2, bl2, Wr2, br2,
                                          W1, W2, b1, b2);
    spmm1_kernel<<<(N_NODES + 3) / 4, 256, 0, stream>>>(
        edge_vals, edge_cols, row_ptr, Abf);
    gemm_fused_kernel<<<GRID_F, 256, 0, stream>>>(Abf, W1, W2, b1, t_buf, r_buf);
    spmm2_kernel<<<(N_NODES + 3) / 4, 256, 0, stream>>>(
        edge_vals, edge_cols, row_ptr, t_buf, r_buf, b2, out);
}

// Round 6
// 132.716 us; speedup vs baseline: 1.1013x; 1.1013x over previous
//
#include <hip/hip_runtime.h>
#include <hip/hip_bf16.h>
#include <math.h>

#define N_NODES 100000
#define N_PAD   100032      // 1563 * 64, multiple of 32
#define F_IN    100
#define HID     128
#define NCLS    64
#define KA      256         // padded K for layer-1 A rows: [agg(100)|0|x(100)|0]
#define XOFF    128         // x part starts at element 128
#define NTILES  (N_PAD / 32)
#define GRID_F  782         // 4 sequential tiles per block

// merged prep kernel block ranges
#define PREPX_BLOCKS  ((N_PAD * 39 + 255) / 256)          // 15255
#define PADZ_BLOCKS   8
#define PREPW_BLOCKS  64
#define ROWPTR_BLOCKS ((N_NODES + 1 + 255) / 256)         // 391
#define PREP_GRID     (PREPX_BLOCKS + PADZ_BLOCKS + PREPW_BLOCKS + ROWPTR_BLOCKS)

typedef __attribute__((ext_vector_type(8))) short bf16x8;
typedef __attribute__((ext_vector_type(4))) float f32x4;

// Pin a loaded value in VGPRs: asm "modifies" it, so the compiler can neither
// rematerialize it from memory nor sink the load to the use point.
#define KEEP(x) asm volatile("" : "+v"(x))

static __device__ __forceinline__ ushort f2bf(float f) {
    union { float f; unsigned u; } v; v.f = f;
    unsigned r = (v.u + 0x7FFFu + ((v.u >> 16) & 1u)) >> 16;
    return (ushort)r;
}
static __device__ __forceinline__ float bflo(unsigned u) {
    union { unsigned u; float f; } v; v.u = u << 16; return v.f;
}
static __device__ __forceinline__ float bfhi(unsigned u) {
    union { unsigned u; float f; } v; v.u = u & 0xFFFF0000u; return v.f;
}
static __device__ __forceinline__ float bf2f(ushort u) {
    union { unsigned u; float f; } v; v.u = ((unsigned)u) << 16; return v.f;
}

// ---- merged prep: x->bf16 staging | pad-row zero | W/b prep | row_ptr ------
// Four independent jobs partitioned by blockIdx range (7 launches -> 4).
__global__ __launch_bounds__(256) void prep_all_kernel(
    const float* __restrict__ x,
    const int* __restrict__ rows, int n_edges,
    const float* __restrict__ Wl1, const float* __restrict__ bl1,
    const float* __restrict__ Wr1, const float* __restrict__ br1,
    const float* __restrict__ Wl2, const float* __restrict__ bl2,
    const float* __restrict__ Wr2, const float* __restrict__ br2,
    ushort* __restrict__ Abf, ushort* __restrict__ W1, ushort* __restrict__ W2,
    float* __restrict__ b1, float* __restrict__ b2,
    int* __restrict__ row_ptr) {
    int b = blockIdx.x;
    if (b < PREPX_BLOCKS) {
        // ---- prep_x: x -> Abf[:, 100:256] bf16 (4 cols per thread) ----
        int i = b * 256 + threadIdx.x;               // over N_PAD * 39
        if (i >= N_PAD * 39) return;
        int node = i / 39;
        int gcol = i - node * 39;
        int col = 100 + gcol * 4;                    // 100..252, step 4
        ushort4 o = {0, 0, 0, 0};
        if (node < N_NODES && col >= XOFF && col < XOFF + F_IN) {
            float4 v = *(const float4*)(x + (size_t)node * F_IN + (col - XOFF));
            o.x = f2bf(v.x); o.y = f2bf(v.y); o.z = f2bf(v.z); o.w = f2bf(v.w);
        }
        *(ushort4*)(Abf + (size_t)node * KA + col) = o;
        return;
    }
    b -= PREPX_BLOCKS;
    if (b < PADZ_BLOCKS) {
        // ---- pad_zero: zero pad-node rows of Abf (cols 0..255) ----
        int i = b * 256 + threadIdx.x;               // over 32 * 64 (8B chunks)
        if (i >= (N_PAD - N_NODES) * (KA / 4)) return;
        ((ushort4*)(Abf + (size_t)N_NODES * KA))[i] = (ushort4){0, 0, 0, 0};
        return;
    }
    b -= PADZ_BLOCKS;
    if (b < PREPW_BLOCKS) {
        // ---- prep_w: weights/bias, bf16, with row interleave ----
        // storage row s -> jorig = (s & ~31) + 2*(s&15) + ((s>>4)&1)
        int tid = b * 256 + threadIdx.x;
        int stride = PREPW_BLOCKS * 256;
        for (int i = tid; i < HID * KA; i += stride) {   // W1: [128][256]
            int s = i >> 8, k = i & 255;
            int j = (s & ~31) + 2 * (s & 15) + ((s >> 4) & 1);
            float v = 0.f;
            if (k < F_IN) v = Wl1[j * F_IN + k];
            else if (k >= XOFF && k < XOFF + F_IN) v = Wr1[j * F_IN + (k - XOFF)];
            W1[i] = f2bf(v);
        }
        for (int i = tid; i < HID * HID; i += stride) {  // W2: [128][128]
            int s = i >> 7, k = i & 127;
            int j = (s & ~31) + 2 * (s & 15) + ((s >> 4) & 1);
            float v = (j < NCLS) ? Wl2[j * HID + k] : Wr2[(j - NCLS) * HID + k];
            W2[i] = f2bf(v);
        }
        if (tid < HID) b1[tid] = bl1[tid] + br1[tid];
        if (tid < NCLS) b2[tid] = bl2[tid] + br2[tid];
        return;
    }
    b -= PREPW_BLOCKS;
    {
        // ---- row_ptr via binary search over sorted rows ----
        int i = b * 256 + threadIdx.x;
        if (i > N_NODES) return;
        int lo = 0, hi = n_edges;
        while (lo < hi) {
            int mid = (lo + hi) >> 1;
            if (rows[mid] < i) lo = mid + 1; else hi = mid;
        }
        row_ptr[i] = lo;
    }
}

// ---- SpMM 1: Abf[node][0:100] = sum_e val * Abf[col][128:228], bf16 --------
// one wave per node, 8-deep gather pipeline (round-3 best: 45.4 us; packing
// variants r4/r5 were neutral-to-worse -> regime is gather-line-traffic-bound)
__global__ __launch_bounds__(256) void spmm1_kernel(
    const float* __restrict__ vals, const int* __restrict__ cols,
    const int* __restrict__ row_ptr, ushort* __restrict__ Abf) {
    int node = blockIdx.x * 4 + (threadIdx.x >> 6);
    if (node >= N_NODES) return;
    int lane = threadIdx.x & 63;
    int s = __builtin_amdgcn_readfirstlane(row_ptr[node]);
    int e = __builtin_amdgcn_readfirstlane(row_ptr[node + 1]);
    if (lane >= 50) return;                      // 50 lanes x 2 feats = 100
    const ushort* xb = Abf + XOFF + lane * 2;

    float accx[4] = {0.f, 0.f, 0.f, 0.f};
    float accy[4] = {0.f, 0.f, 0.f, 0.f};
    int i = s;
    for (; i + 8 <= e; i += 8) {
        float v[8]; unsigned u[8];
#pragma unroll
        for (int q = 0; q < 8; ++q) {
            v[q] = vals[i + q];
            u[q] = *(const unsigned*)(xb + (size_t)cols[i + q] * KA);
        }
#pragma unroll
        for (int q = 0; q < 8; ++q) {
            accx[q & 3] += v[q] * bflo(u[q]);
            accy[q & 3] += v[q] * bfhi(u[q]);
        }
    }
    if (i + 4 <= e) {
        float v[4]; unsigned u[4];
#pragma unroll
        for (int q = 0; q < 4; ++q) {
            v[q] = vals[i + q];
            u[q] = *(const unsigned*)(xb + (size_t)cols[i + q] * KA);
        }
#pragma unroll
        for (int q = 0; q < 4; ++q) {
            accx[q] += v[q] * bflo(u[q]);
            accy[q] += v[q] * bfhi(u[q]);
        }
        i += 4;
    }
    for (; i < e; ++i) {
        float v = vals[i];
        unsigned u = *(const unsigned*)(xb + (size_t)cols[i] * KA);
        accx[0] += v * bflo(u);
        accy[0] += v * bfhi(u);
    }
    float ax = (accx[0] + accx[1]) + (accx[2] + accx[3]);
    float ay = (accy[0] + accy[1]) + (accy[2] + accy[3]);
    unsigned o = ((unsigned)f2bf(ay) << 16) | (unsigned)f2bf(ax);
    *(unsigned*)(Abf + (size_t)node * KA + lane * 2) = o;
}

// ---- Fused GEMM: LDS-staged A (shared by 4 waves), KEEP-pinned W -----------
// Block: 4 waves, 4 sequential 32-node tiles. Per tile:
//   - A-tile (32x256 bf16 = 16KB) staged ONCE into LDS (coalesced
//     global_load_dwordx4 -> XOR-swizzled ds_write_b128), read by all 4
//     waves via swizzled ds_read_b128 (2-way bank alias = free).
//   - W frags pinned in VGPRs via KEEP asm (prevents the compiler's
//     min-pressure schedule that re-loads W before every MFMA: r2 showed
//     VGPR_Count=44 with every fragment load sunk to its use).
//   - L1-norm deferred to the epilogue; one barrier per tile; A/h/part
//     double-buffered so tiles pipeline without a bottom barrier.
__global__ __launch_bounds__(256, 2) void gemm_fused_kernel(
    const ushort* __restrict__ Abf, const ushort* __restrict__ W1,
    const ushort* __restrict__ W2, const float* __restrict__ b1,
    ushort* __restrict__ t, ushort* __restrict__ rb) {
    __shared__ char Ald[2][16384];                   // dbuf: 32 nodes x 256 bf16
    __shared__ char h_lds[2][8192];                  // dbuf: 32 nodes x 128 bf16
    __shared__ __align__(16) float part[2][32][4];   // [buf][node][wave] L1 partials
    int lane = threadIdx.x & 63;
    int w = threadIdx.x >> 6;
    int m = lane & 15, g = lane >> 4;

    int t0 = blockIdx.x * 4;
    int ntl = NTILES - t0; if (ntl > 4) ntl = 4;     // 1..4 tiles (last block: 2)

    // ---- W frags: loaded once, pinned ----
    bf16x8 wf1[2][8];
    bf16x8 wf2[2][4];
#pragma unroll
    for (int o = 0; o < 2; ++o) {
        const ushort* wrow = W1 + (size_t)(w * 32 + o * 16 + m) * KA + g * 8;
#pragma unroll
        for (int kb = 0; kb < 8; ++kb) wf1[o][kb] = *(const bf16x8*)(wrow + kb * 32);
    }
#pragma unroll
    for (int o = 0; o < 2; ++o) {
        const ushort* wrow = W2 + (size_t)(w * 32 + o * 16 + m) * HID + g * 8;
#pragma unroll
        for (int kb = 0; kb < 4; ++kb) wf2[o][kb] = *(const bf16x8*)(wrow + kb * 32);
    }
#pragma unroll
    for (int o = 0; o < 2; ++o) {
#pragma unroll
        for (int kb = 0; kb < 8; ++kb) KEEP(wf1[o][kb]);
#pragma unroll
        for (int kb = 0; kb < 4; ++kb) KEEP(wf2[o][kb]);
    }
    float bias0 = b1[w * 32 + 2 * m + 0];
    float bias1 = b1[w * 32 + 2 * m + 1];

    // ---- prologue: stage tile t0 into Ald[0] ----
    bf16x8 st[4];
#pragma unroll
    for (int i = 0; i < 4; ++i)
        st[i] = *(const bf16x8*)(Abf + (size_t)t0 * 8192 + ((w * 4 + i) * 64 + lane) * 8);
#pragma unroll
    for (int i = 0; i < 4; ++i) {
        int r = w * 4 + i;
        int nl = r * 2 + (lane >> 5);
        int dst = nl * 512 + ((((lane & 31) ^ (nl & 7))) << 4);
        *(bf16x8*)(&Ald[0][0] + dst) = st[i];
    }
    __syncthreads();

    for (int j = 0; ; ) {
        int buf = j & 1;
        int base = (t0 + j) * 32;
        bool last = (j + 1 >= ntl);

        // ---- issue next tile's global loads (hide under phase 1) ----
        if (!last) {
#pragma unroll
            for (int i = 0; i < 4; ++i)
                st[i] = *(const bf16x8*)(Abf + (size_t)(t0 + j + 1) * 8192 +
                                         ((w * 4 + i) * 64 + lane) * 8);
        }

        // ---- phase 1: layer-1 MFMAs, A from LDS (swizzled reads) ----
        f32x4 acc1[2][2];
#pragma unroll
        for (int mt = 0; mt < 2; ++mt)
#pragma unroll
            for (int o = 0; o < 2; ++o) acc1[mt][o] = (f32x4){0.f, 0.f, 0.f, 0.f};
#pragma unroll
        for (int mt = 0; mt < 2; ++mt) {
            int nl = mt * 16 + m;
            int rowb = nl * 512;
            int swz = (nl & 7) << 4;
#pragma unroll
            for (int kb = 0; kb < 8; ++kb) {
                bf16x8 a = *(const bf16x8*)(&Ald[buf][0] + rowb + ((((g + 4 * kb)) << 4) ^ swz));
                acc1[mt][0] = __builtin_amdgcn_mfma_f32_16x16x32_bf16(a, wf1[0][kb], acc1[mt][0], 0, 0, 0);
                acc1[mt][1] = __builtin_amdgcn_mfma_f32_16x16x32_bf16(a, wf1[1][kb], acc1[mt][1], 0, 0, 0);
            }
        }

        // ---- write next A-tile into the other LDS buffer ----
        if (!last) {
#pragma unroll
            for (int i = 0; i < 4; ++i) {
                int r = w * 4 + i;
                int nl = r * 2 + (lane >> 5);
                int dst = nl * 512 + ((((lane & 31) ^ (nl & 7))) << 4);
                *(bf16x8*)(&Ald[buf ^ 1][0] + dst) = st[i];
            }
        }

        // ---- bias; relu(h) -> h_lds (UN-normalized); partial L1 ----
        float sr[2][4];
#pragma unroll
        for (int mt = 0; mt < 2; ++mt)
#pragma unroll
            for (int r = 0; r < 4; ++r) {
                acc1[mt][0][r] += bias0;
                acc1[mt][1][r] += bias1;
                sr[mt][r] = fabsf(acc1[mt][0][r]) + fabsf(acc1[mt][1][r]);
                int nl = mt * 16 + g * 4 + r;
                unsigned lo = f2bf(fmaxf(acc1[mt][0][r], 0.f));
                unsigned hi = f2bf(fmaxf(acc1[mt][1][r], 0.f));
                int off = (nl * 256 + w * 64 + m * 4) ^ ((nl & 7) << 4);
                *(unsigned*)(&h_lds[buf][0] + off) = (hi << 16) | lo;
            }
#pragma unroll
        for (int off = 1; off < 16; off <<= 1)
#pragma unroll
            for (int mt = 0; mt < 2; ++mt)
#pragma unroll
                for (int r = 0; r < 4; ++r) sr[mt][r] += __shfl_xor(sr[mt][r], off);
        if (m == 0) {
#pragma unroll
            for (int mt = 0; mt < 2; ++mt)
#pragma unroll
                for (int r = 0; r < 4; ++r) part[buf][mt * 16 + g * 4 + r][w] = sr[mt][r];
        }
        __syncthreads();        // single barrier/tile: h+part+next-A visible

        // ---- phase 2: layer-2 MFMAs from LDS relu(h) ----
        f32x4 acc2[2][2];
#pragma unroll
        for (int mt = 0; mt < 2; ++mt)
#pragma unroll
            for (int o = 0; o < 2; ++o) acc2[mt][o] = (f32x4){0.f, 0.f, 0.f, 0.f};
#pragma unroll
        for (int mt = 0; mt < 2; ++mt) {
            int nl = mt * 16 + m;
            bf16x8 a[4];
#pragma unroll
            for (int kb = 0; kb < 4; ++kb) {
                int off = (nl * 256 + g * 16 + kb * 64) ^ ((nl & 7) << 4);
                a[kb] = *(const bf16x8*)(&h_lds[buf][0] + off);
            }
#pragma unroll
            for (int kb = 0; kb < 4; ++kb) {
                acc2[mt][0] = __builtin_amdgcn_mfma_f32_16x16x32_bf16(a[kb], wf2[0][kb], acc2[mt][0], 0, 0, 0);
                acc2[mt][1] = __builtin_amdgcn_mfma_f32_16x16x32_bf16(a[kb], wf2[1][kb], acc2[mt][1], 0, 0, 0);
            }
        }

        // ---- epilogue: deferred 1/||h||_1, packed dword stores ----
        ushort* obuf = (w < 2) ? t : rb;
        int colb = (w & 1) * 32 + 2 * m;
#pragma unroll
        for (int mt = 0; mt < 2; ++mt)
#pragma unroll
            for (int r = 0; r < 4; ++r) {
                int nl = mt * 16 + g * 4 + r;
                int node = base + nl;
                float4 p = *(const float4*)&part[buf][nl][0];
                float inv = 1.f / fmaxf((p.x + p.y) + (p.z + p.w), 1e-12f);
                unsigned lo = f2bf(acc2[mt][0][r] * inv);
                unsigned hi = f2bf(acc2[mt][1][r] * inv);
                *(unsigned*)(obuf + (size_t)node * NCLS + colb) = (hi << 16) | lo;
            }

        if (last) break;
        ++j;
    }
}

// ---- SpMM 2 on t (bf16, D=64) + rb + bias, fused log_softmax ---------------
// one wave per node, 8-deep gather pipeline (round-3 best: 43.1 us)
__global__ __launch_bounds__(256) void spmm2_kernel(
    const float* __restrict__ vals, const int* __restrict__ cols,
    const int* __restrict__ row_ptr, const ushort* __restrict__ t,
    const ushort* __restrict__ rb, const float* __restrict__ b2,
    float* __restrict__ out) {
    int node = blockIdx.x * 4 + (threadIdx.x >> 6);
    if (node >= N_NODES) return;
    int lane = threadIdx.x & 63;
    int s = __builtin_amdgcn_readfirstlane(row_ptr[node]);
    int e = __builtin_amdgcn_readfirstlane(row_ptr[node + 1]);

    float a4[4] = {0.f, 0.f, 0.f, 0.f};
    int i = s;
    for (; i + 8 <= e; i += 8) {
        float v[8], tv[8];
#pragma unroll
        for (int q = 0; q < 8; ++q) {
            v[q] = vals[i + q];
            tv[q] = bf2f(t[(size_t)cols[i + q] * NCLS + lane]);
        }
#pragma unroll
        for (int q = 0; q < 8; ++q) a4[q & 3] += v[q] * tv[q];
    }
    if (i + 4 <= e) {
        float v[4], tv[4];
#pragma unroll
        for (int q = 0; q < 4; ++q) {
            v[q] = vals[i + q];
            tv[q] = bf2f(t[(size_t)cols[i + q] * NCLS + lane]);
        }
#pragma unroll
        for (int q = 0; q < 4; ++q) a4[q] += v[q] * tv[q];
        i += 4;
    }
    for (; i < e; ++i) a4[0] += vals[i] * bf2f(t[(size_t)cols[i] * NCLS + lane]);
    float acc = (a4[0] + a4[1]) + (a4[2] + a4[3]);
    acc += bf2f(rb[(size_t)node * NCLS + lane]) + b2[lane];

    float mx = acc;
#pragma unroll
    for (int off = 32; off; off >>= 1) mx = fmaxf(mx, __shfl_xor(mx, off));
    float ex = expf(acc - mx);
    float ss = ex;
#pragma unroll
    for (int off = 32; off; off >>= 1) ss += __shfl_xor(ss, off);
    out[(size_t)node * NCLS + lane] = acc - mx - logf(ss);
}

extern "C" void kernel_launch(void* const* d_in, const int* in_sizes, int n_in,
                              void* d_out, int out_size, void* d_ws, size_t ws_size,
                              hipStream_t stream) {
    const float* x         = (const float*)d_in[0];
    const float* edge_vals = (const float*)d_in[1];
    const float* Wl1       = (const float*)d_in[2];
    const float* bl1       = (const float*)d_in[3];
    const float* Wr1       = (const float*)d_in[4];
    const float* br1       = (const float*)d_in[5];
    const float* Wl2       = (const float*)d_in[6];
    const float* bl2       = (const float*)d_in[7];
    const float* Wr2       = (const float*)d_in[8];
    const float* br2       = (const float*)d_in[9];
    const int* edge_rows   = (const int*)d_in[10];
    const int* edge_cols   = (const int*)d_in[11];
    float* out = (float*)d_out;

    int n_edges = in_sizes[1];

    char* ws = (char*)d_ws;
    int*    row_ptr = (int*)(ws + 0);                        // 400 KB
    ushort* Abf     = (ushort*)(ws + (1u << 20));            // N_PAD*256*2 = 51.2 MB
    ushort* t_buf   = (ushort*)(ws + 52264960u);             // N_PAD*64*2 = 12.8 MB
    ushort* r_buf   = (ushort*)(ws + 65069056u);             // 12.8 MB
    ushort* W1      = (ushort*)(ws + 77873152u);             // 64 KB
    ushort* W2      = (ushort*)(ws + 77938688u);             // 32 KB
    float*  b1      = (float*)(ws + 77971456u);              // 512 B
    float*  b2      = (float*)(ws + 77971968u);              // 256 B

    prep_all_kernel<<<PREP_GRID, 256, 0, stream>>>(
        x, edge_rows, n_edges, Wl1, bl1, Wr1, br1, Wl2, bl2, Wr2, br2,
        Abf, W1, W2, b1, b2, row_ptr);
    spmm1_kernel<<<(N_NODES + 3) / 4, 256, 0, stream>>>(
        edge_vals, edge_cols, row_ptr, Abf);
    gemm_fused_kernel<<<GRID_F, 256, 0, stream>>>(Abf, W1, W2, b1, t_buf, r_buf);
    spmm2_kernel<<<(N_NODES + 3) / 4, 256, 0, stream>>>(
        edge_vals, edge_cols, row_ptr, t_buf, r_buf, b2, out);
}